// Round 1
// baseline (388.076 us; speedup 1.0000x reference)
//
#include <hip/hip_runtime.h>
#include <cstdint>

// Problem constants (fixed instance: B=8192, Cin=4096, Cout=1024, T=10)
#define B_DIM 8192
#define CIN   4096
#define COUT  1024
#define NPLN  3072   // 3 digit planes stacked along N

// Fixed-point quantization of W: 23-bit minus headroom so top balanced digit <= 127.
// W in [0, 0.1]; W_q = round_rn(W * W_SCALE), W_q in [0, QMAX].
constexpr double W_SCALE   = 83230720.0;        // (2^23 - 2^16) / 0.1
constexpr int    QMAX      = 8323072;           // 2^23 - 2^16
constexpr double INV_SCALE = 0.1 / 8323072.0;   // 1 / W_SCALE

using i32x4 = __attribute__((ext_vector_type(4))) int;

// ---- async global->LDS, 16B per lane. LDS dest is wave-uniform base + lane*16.
__device__ __forceinline__ void async_copy16(void* lds, const void* g) {
    auto l = (__attribute__((address_space(3))) void*)(uintptr_t)(lds);
    auto p = (const __attribute__((address_space(1))) void*)(uintptr_t)(g);
    __builtin_amdgcn_global_load_lds(p, l, 16, 0, 0);
}

// ---------------------------------------------------------------------------
// Kernel 1: x (fp32 0/1) -> i8. 16 elements per thread.
__global__ void prep_x(const float* __restrict__ x, int8_t* __restrict__ Ai) {
    const int idx = blockIdx.x * 256 + threadIdx.x;      // 2,097,152 threads
    const float4* xp = (const float4*)x + (size_t)idx * 4;
    float4 v0 = xp[0], v1 = xp[1], v2 = xp[2], v3 = xp[3];
    auto pk = [](float a, float b, float c, float d) -> int {
        return (a != 0.f ? 1 : 0) | ((b != 0.f ? 1 : 0) << 8) |
               ((c != 0.f ? 1 : 0) << 16) | ((d != 0.f ? 1 : 0) << 24);
    };
    int4 r;
    r.x = pk(v0.x, v0.y, v0.z, v0.w);
    r.y = pk(v1.x, v1.y, v1.z, v1.w);
    r.z = pk(v2.x, v2.y, v2.z, v2.w);
    r.w = pk(v3.x, v3.y, v3.z, v3.w);
    ((int4*)Ai)[idx] = r;
}

// ---------------------------------------------------------------------------
// Kernel 2: W (fp32) -> 3 balanced base-256 digit planes (i8), stacked N-major.
// Also zero-inits colmax bits (runs before gemm/colmax on the same stream).
__global__ void prep_w(const float* __restrict__ W, int8_t* __restrict__ Bd,
                       unsigned long long* __restrict__ cm) {
    const int idx = blockIdx.x * 256 + threadIdx.x;      // 1,048,576 threads, 4 elems each
    float4 w = ((const float4*)W)[idx];
    float ws[4] = {w.x, w.y, w.z, w.w};
    char dg[3][4];
#pragma unroll
    for (int k = 0; k < 4; ++k) {
        int qv = __double2int_rn((double)ws[k] * W_SCALE);
        qv = max(0, min(QMAX, qv));
        int d0 = ((qv + 128) & 255) - 128; int tq = (qv - d0) >> 8;
        int d1 = ((tq + 128) & 255) - 128; int d2 = (tq - d1) >> 8;   // d2 in [0,127]
        dg[0][k] = (char)d0; dg[1][k] = (char)d1; dg[2][k] = (char)d2;
    }
    const size_t off = (size_t)idx * 4;  // = j*4096 + c (no row crossing: 4096 % 4 == 0)
#pragma unroll
    for (int p = 0; p < 3; ++p) {
        char4 c4; c4.x = dg[p][0]; c4.y = dg[p][1]; c4.z = dg[p][2]; c4.w = dg[p][3];
        *(char4*)(Bd + (size_t)p * COUT * CIN + off) = c4;
    }
    if (idx < COUT) cm[idx] = 0ull;
}

// ---------------------------------------------------------------------------
// Kernel 3: i8 GEMM  S[8192][3072] = Ai[8192][4096] * Bd[3072][4096]^T  (i32 exact)
// m97 structure: 128x128 tile, BK=64, 256 thr (4 waves, 64x64 each),
// global_load_lds width 16, XOR chunk swizzle s(r) = (r>>1)&3 (2-way aliasing = free).
__global__ __launch_bounds__(256, 2) void gemm_i8(const int8_t* __restrict__ A,
                                                  const int8_t* __restrict__ Bm,
                                                  int* __restrict__ S) {
    __shared__ alignas(16) int8_t As[128 * 64];
    __shared__ alignas(16) int8_t Bs[128 * 64];
    const int tid  = threadIdx.x;
    const int lane = tid & 63;
    const int wave = tid >> 6;
    const int wr = wave >> 1, wc = wave & 1;
    const int bn = blockIdx.x, bm = blockIdx.y;

    // staging: thread t owns LDS slot (r = t>>2, c' = t&3); it fetches global chunk c'^s(r)
    const int r0  = tid >> 2;
    const int c0  = tid & 3;
    const int gc0 = c0 ^ ((r0 >> 1) & 3);
    const int r1  = r0 + 64;
    const int gc1 = c0 ^ ((r1 >> 1) & 3);
    const int8_t* Ag0 = A  + (size_t)(bm * 128 + r0) * CIN + gc0 * 16;
    const int8_t* Ag1 = A  + (size_t)(bm * 128 + r1) * CIN + gc1 * 16;
    const int8_t* Bg0 = Bm + (size_t)(bn * 128 + r0) * CIN + gc0 * 16;
    const int8_t* Bg1 = Bm + (size_t)(bn * 128 + r1) * CIN + gc1 * 16;
    int8_t* AsW = As + wave * 1024;   // iter-0 base for this wave (+4096 for iter 1)
    int8_t* BsW = Bs + wave * 1024;

    // fragment read offsets (A[m=lane&15][k=(lane>>4)*16+j] family layout)
    const int mrow = lane & 15;
    const int q    = lane >> 4;
    const int sw   = (mrow >> 1) & 3;
    const int aoff = (wr * 64 + mrow) * 64 + (q ^ sw) * 16;   // + mt*1024
    const int boff = (wc * 64 + mrow) * 64 + (q ^ sw) * 16;   // + nt*1024

    i32x4 acc[4][4] = {};
    for (int kc = 0; kc < CIN; kc += 64) {
        __syncthreads();
        async_copy16(AsW,        Ag0 + kc);
        async_copy16(AsW + 4096, Ag1 + kc);
        async_copy16(BsW,        Bg0 + kc);
        async_copy16(BsW + 4096, Bg1 + kc);
        __syncthreads();
        i32x4 a[4], b[4];
#pragma unroll
        for (int t = 0; t < 4; ++t) a[t] = *(const i32x4*)(As + aoff + t * 1024);
#pragma unroll
        for (int t = 0; t < 4; ++t) b[t] = *(const i32x4*)(Bs + boff + t * 1024);
#pragma unroll
        for (int mt = 0; mt < 4; ++mt)
#pragma unroll
            for (int nt = 0; nt < 4; ++nt)
                acc[mt][nt] = __builtin_amdgcn_mfma_i32_16x16x64_i8(a[mt], b[nt], acc[mt][nt], 0, 0, 0);
    }

    // epilogue: C/D layout col = lane&15 (N), row = (lane>>4)*4 + reg (M)
    const int gm0 = bm * 128 + wr * 64 + q * 4;
    const int gn0 = bn * 128 + wc * 64 + mrow;
#pragma unroll
    for (int mt = 0; mt < 4; ++mt)
#pragma unroll
        for (int nt = 0; nt < 4; ++nt) {
            const int gn = gn0 + nt * 16;
#pragma unroll
            for (int reg = 0; reg < 4; ++reg) {
                const int gm = gm0 + mt * 16 + reg;
                S[(size_t)gm * NPLN + gn] = acc[mt][nt][reg];
            }
        }
}

// ---------------------------------------------------------------------------
// Kernel 4: column max of i (fp64) via monotone-bits atomicMax (i >= 0).
__global__ void colmax_k(const int* __restrict__ S, unsigned long long* __restrict__ cm) {
    const int j = blockIdx.x * 256 + threadIdx.x;
    const int rbeg = blockIdx.y * 128;
    double m = 0.0;
    for (int r = rbeg; r < rbeg + 128; ++r) {
        const int* row = S + (size_t)r * NPLN;
        long long s0 = row[j], s1 = row[COUT + j], s2 = row[2 * COUT + j];
        long long isum = s0 + s1 * 256 + s2 * 65536;
        double v = (double)isum * INV_SCALE;
        m = fmax(m, v);
    }
    atomicMax(cm + j, (unsigned long long)__double_as_longlong(m));
}

// ---------------------------------------------------------------------------
// Kernel 5: LIF/WTA scan, one wave per batch row, 16 fp64 neurons per lane,
// shuffle-only reductions, everything in registers. Matches reference fp64 ops.
__global__ void scan_k(const int* __restrict__ S, const unsigned long long* __restrict__ cm,
                       const int* __restrict__ twp, float* __restrict__ out) {
    const int lane = threadIdx.x & 63;
    const int wave = threadIdx.x >> 6;
    const int b = blockIdx.x * 4 + wave;
    const int T = *twp;
    const int* row = S + (size_t)b * NPLN;

    double iv[16], mem[16], thr[16];
    int cnt[16];
    double imax = 0.0;
#pragma unroll
    for (int u = 0; u < 16; ++u) {
        const int j = lane + u * 64;
        long long s0 = row[j], s1 = row[COUT + j], s2 = row[2 * COUT + j];
        long long isum = s0 + s1 * 256 + s2 * 65536;
        iv[u]  = (double)isum * INV_SCALE;
        thr[u] = 3.0 * __longlong_as_double((long long)cm[j]);
        mem[u] = 0.0; cnt[u] = 0;
        imax = fmax(imax, iv[u]);
    }
#pragma unroll
    for (int d = 32; d >= 1; d >>= 1) imax = fmax(imax, __shfl_xor(imax, d, 64));
    const double h = 1.625 * imax;   // INH * imax, rounded once like the reference

    for (int t = 0; t < T; ++t) {
        int first = 0x7fffffff;
        bool sp[16];
#pragma unroll
        for (int u = 0; u < 16; ++u) {
            mem[u] = mem[u] * 0.99 + iv[u];
            sp[u] = mem[u] > thr[u];
            if (sp[u]) first = min(first, lane + u * 64);
        }
#pragma unroll
        for (int d = 32; d >= 1; d >>= 1) first = min(first, __shfl_xor(first, d, 64));
        const bool rowspike = first < 0x7fffffff;
#pragma unroll
        for (int u = 0; u < 16; ++u) {
            if (sp[u]) mem[u] = 0.0;                    // hard reset at spikers
            if (rowspike) {
                if (lane + u * 64 == first) cnt[u]++;   // WTA winner (first index)
                else mem[u] -= h;                       // lateral inhibition
            }
        }
    }
#pragma unroll
    for (int u = 0; u < 16; ++u)
        out[(size_t)b * COUT + lane + u * 64] = (float)cnt[u];
}

// ---------------------------------------------------------------------------
extern "C" void kernel_launch(void* const* d_in, const int* in_sizes, int n_in,
                              void* d_out, int out_size, void* d_ws, size_t ws_size,
                              hipStream_t stream) {
    const float* x  = (const float*)d_in[0];
    const float* W  = (const float*)d_in[1];
    const int*   tw = (const int*)d_in[2];
    float* out = (float*)d_out;

    int8_t* Ai = (int8_t*)d_ws;                                   // 33,554,432 B
    int8_t* Bd = Ai + (size_t)B_DIM * CIN;                        // 12,582,912 B
    int*    S  = (int*)(Bd + (size_t)NPLN * CIN);                 // 100,663,296 B
    unsigned long long* cm =
        (unsigned long long*)((int8_t*)S + (size_t)B_DIM * NPLN * 4);  // 8,192 B

    hipLaunchKernelGGL(prep_x,   dim3(8192),   dim3(256), 0, stream, x, Ai);
    hipLaunchKernelGGL(prep_w,   dim3(4096),   dim3(256), 0, stream, W, Bd, cm);
    hipLaunchKernelGGL(gemm_i8,  dim3(24, 64), dim3(256), 0, stream, Ai, Bd, S);
    hipLaunchKernelGGL(colmax_k, dim3(4, 64),  dim3(256), 0, stream, S, cm);
    hipLaunchKernelGGL(scan_k,   dim3(2048),   dim3(256), 0, stream, S, cm, tw, out);
}